// Round 6
// baseline (367.366 us; speedup 1.0000x reference)
//
#include <hip/hip_runtime.h>

#define T_ 2048
#define HID_ 2048
#define H_ 16
#define KV_ 8
#define G_ 2
#define D_ 128
#define GH_ 128
#define BS_ 64
#define NB_ 32
#define START_ 409
#define TG0_ 384
#define SCALE_ 0.08838834764831845f  // 1/sqrt(128), also 1/sqrt(GH)
#define MFIX_ 8.0f  // fixed softmax max: |logit| <= 128*SCALE = 11.31 (q,k rmsnormed)
#define HT_ 32768   // H_*T_

typedef __attribute__((ext_vector_type(8))) short short8_t;
typedef __attribute__((ext_vector_type(4))) float float4_t;
typedef __attribute__((ext_vector_type(8))) unsigned short ushort8_t;
typedef __attribute__((ext_vector_type(4))) unsigned short ushort4_t;

// ---------- helpers ----------
__device__ __forceinline__ float wave_sum(float v) {
#pragma unroll
  for (int o = 32; o > 0; o >>= 1) v += __shfl_xor(v, o, 64);
  return v;
}
__device__ __forceinline__ unsigned short f2bf(float x) {
  unsigned int u = __float_as_uint(x);
  unsigned int r = (u + 0x7fffu + ((u >> 16) & 1u)) >> 16;
  return (unsigned short)r;
}
__device__ __forceinline__ float bf2f(unsigned short h) {
  return __uint_as_float(((unsigned int)h) << 16);
}

// async global->LDS 16B/lane; LDS dest = wave-uniform base + lane*16
__device__ __forceinline__ void gload16(const void* g, void* l) {
  __builtin_amdgcn_global_load_lds((const __attribute__((address_space(1))) unsigned int*)g,
                                   (__attribute__((address_space(3))) unsigned int*)l, 16, 0, 0);
}

// ---------- 64x64 cast+transpose tile (device) ----------
__device__ __forceinline__ void castT_dev(const float* __restrict__ in,
                                          unsigned short* __restrict__ out, int K, int N,
                                          int ldin, int bx, int by,
                                          unsigned short (*tile)[72], int tid) {
  int k0 = by * 64, n0 = bx * 64;
  int tx = tid & 63, ty4 = tid >> 6;
#pragma unroll
  for (int i = 0; i < 16; ++i) {
    int ky = ty4 * 16 + i;
    tile[tx][ky] = f2bf(in[(size_t)(k0 + ky) * ldin + n0 + tx]);
  }
  __syncthreads();
#pragma unroll
  for (int i = 0; i < 16; ++i) {
    int ny = ty4 * 16 + i;
    out[(size_t)(n0 + ny) * K + k0 + tx] = tile[ny][tx];
  }
}

__global__ __launch_bounds__(256) void castT(const float* __restrict__ in,
                                             unsigned short* __restrict__ out,
                                             int K, int N, int ldin) {
  __shared__ unsigned short tile[64][72];
  castT_dev(in, out, K, N, ldin, blockIdx.x, blockIdx.y, tile, threadIdx.x);
}

// ---------- fused prologue: hs cast + all weight cast-transposes ----------
__global__ __launch_bounds__(256) void prep_cast(const float* __restrict__ hs,
                                                 const float* __restrict__ Wq,
                                                 const float* __restrict__ Wk,
                                                 const float* __restrict__ Wv,
                                                 const float* __restrict__ Wo,
                                                 const float* __restrict__ gwq,
                                                 const float* __restrict__ gwk,
                                                 unsigned short* __restrict__ hsb,
                                                 unsigned short* __restrict__ WqkvT,
                                                 unsigned short* __restrict__ WoT,
                                                 unsigned short* __restrict__ gwqT,
                                                 unsigned short* __restrict__ gwkT) {
  __shared__ unsigned short tile[64][72];
  int id = blockIdx.x, tid = threadIdx.x;
  if (id < 4096) {
    int i = id * 256 + tid;
    float4 v = ((const float4*)hs)[i];
    ushort4_t o = {f2bf(v.x), f2bf(v.y), f2bf(v.z), f2bf(v.w)};
    *(ushort4_t*)(hsb + (size_t)i * 4) = o;
  } else if (id < 5120) {
    int t = id - 4096;
    castT_dev(Wq, WqkvT, 2048, 2048, 2048, t & 31, t >> 5, tile, tid);
  } else if (id < 5632) {
    int t = id - 5120;
    castT_dev(Wk, WqkvT + (size_t)2048 * 2048, 2048, 1024, 1024, t & 15, t >> 4, tile, tid);
  } else if (id < 6144) {
    int t = id - 5632;
    castT_dev(Wv, WqkvT + (size_t)3072 * 2048, 2048, 1024, 1024, t & 15, t >> 4, tile, tid);
  } else if (id < 7168) {
    int t = id - 6144;
    castT_dev(Wo, WoT, 2048, 2048, 2048, t & 31, t >> 5, tile, tid);
  } else if (id < 7172) {
    int t = id - 7168;
    castT_dev(gwq, gwqT, 128, 128, 128, t & 1, t >> 1, tile, tid);
  } else {
    int t = id - 7172;
    castT_dev(gwk, gwkT, 128, 128, 128, t & 1, t >> 1, tile, tid);
  }
}

// ---------- bf16 MFMA GEMM v3: BK=64, swizzled conflict-free LDS ----------
__global__ __launch_bounds__(256) void gemm_bf16_v3(const unsigned short* __restrict__ A,
                                                    const unsigned short* __restrict__ Bt,
                                                    float* __restrict__ C,
                                                    int M, int N, int K, int ldc) {
  __shared__ unsigned short As[128 * 64];
  __shared__ unsigned short Bs[128 * 64];
  int tid = threadIdx.x;
  int wid = tid >> 6, lane = tid & 63;
  int quad = lane >> 4, l16 = lane & 15;
  int wm = wid & 1, wn = wid >> 1;
  int m0 = blockIdx.y * 128, n0 = blockIdx.x * 128;
  const unsigned short* gA[4];
  const unsigned short* gB[4];
#pragma unroll
  for (int it = 0; it < 4; ++it) {
    int line = wid * 32 + it * 8 + (lane >> 3);
    int chunk = (lane & 7) ^ (line & 7);
    gA[it] = A + (size_t)(m0 + line) * K + chunk * 8;
    gB[it] = Bt + (size_t)(n0 + line) * K + chunk * 8;
  }
  float4_t acc[4][4];
#pragma unroll
  for (int i = 0; i < 4; ++i)
#pragma unroll
    for (int j = 0; j < 4; ++j) acc[i][j] = (float4_t){0.f, 0.f, 0.f, 0.f};
  for (int k0 = 0; k0 < K; k0 += 64) {
    __syncthreads();
#pragma unroll
    for (int it = 0; it < 4; ++it) {
      gload16(gA[it] + k0, As + (wid * 32 + it * 8) * 64);
      gload16(gB[it] + k0, Bs + (wid * 32 + it * 8) * 64);
    }
    __syncthreads();
    short8_t a[2][4], b[2][4];
#pragma unroll
    for (int ks = 0; ks < 2; ++ks) {
      int sw = ((ks * 4 + quad) ^ (l16 & 7)) * 8;
#pragma unroll
      for (int i = 0; i < 4; ++i) {
        a[ks][i] = *(const short8_t*)&As[(wm * 64 + i * 16 + l16) * 64 + sw];
        b[ks][i] = *(const short8_t*)&Bs[(wn * 64 + i * 16 + l16) * 64 + sw];
      }
    }
#pragma unroll
    for (int ks = 0; ks < 2; ++ks)
#pragma unroll
      for (int i = 0; i < 4; ++i)
#pragma unroll
        for (int j = 0; j < 4; ++j)
          acc[i][j] = __builtin_amdgcn_mfma_f32_16x16x32_bf16(a[ks][i], b[ks][j], acc[i][j], 0, 0, 0);
  }
#pragma unroll
  for (int i = 0; i < 4; ++i)
#pragma unroll
    for (int j = 0; j < 4; ++j)
#pragma unroll
      for (int reg = 0; reg < 4; ++reg)
        C[(size_t)(m0 + wm * 64 + i * 16 + quad * 4 + reg) * ldc + n0 + wn * 64 + j * 16 + l16] =
            acc[i][j][reg];
}

// ---------- fused q/k rmsnorm + rope (+q pool) ----------
__global__ __launch_bounds__(128) void norm_rope_fused(const float* __restrict__ qkvf,
                                                       const float* __restrict__ qw,
                                                       const float* __restrict__ kw,
                                                       const float* __restrict__ cosT,
                                                       const float* __restrict__ sinT,
                                                       unsigned short* __restrict__ qbf,
                                                       unsigned short* __restrict__ qpool_bf,
                                                       unsigned short* __restrict__ kbf,
                                                       float* __restrict__ knorm) {
  int t = blockIdx.x, d = threadIdx.x;
  if (blockIdx.y < 8) {
    int kv = blockIdx.y;
    size_t i0 = (size_t)t * 4096 + (kv * G_) * D_ + d;
    float x0 = qkvf[i0], x1 = qkvf[i0 + D_];
    __shared__ float sred[2][2];
    float s0 = wave_sum(x0 * x0), s1 = wave_sum(x1 * x1);
    if ((d & 63) == 0) { sred[0][d >> 6] = s0; sred[1][d >> 6] = s1; }
    __syncthreads();
    float wv = qw[d];
    float n0 = x0 * rsqrtf((sred[0][0] + sred[0][1]) * (1.f / D_) + 1e-6f) * wv;
    float n1 = x1 * rsqrtf((sred[1][0] + sred[1][1]) * (1.f / D_) + 1e-6f) * wv;
    if (t >= TG0_) qpool_bf[((size_t)(t - TG0_) * KV_ + kv) * D_ + d] = f2bf(0.5f * (n0 + n1));
    __shared__ float sh[2][D_];
    sh[0][d] = n0; sh[1][d] = n1;
    __syncthreads();
    float c = cosT[t * D_ + d], s = sinT[t * D_ + d];
    float r0 = (d < 64) ? -sh[0][d + 64] : sh[0][d - 64];
    float r1 = (d < 64) ? -sh[1][d + 64] : sh[1][d - 64];
    qbf[((size_t)(t * H_) + kv * G_) * D_ + d] = f2bf(n0 * c + r0 * s);
    qbf[((size_t)(t * H_) + kv * G_ + 1) * D_ + d] = f2bf(n1 * c + r1 * s);
  } else {
    int kv = blockIdx.y - 8;
    float x = qkvf[(size_t)t * 4096 + 2048 + kv * D_ + d];
    __shared__ float sredk[2];
    float s0 = wave_sum(x * x);
    if ((d & 63) == 0) sredk[d >> 6] = s0;
    __syncthreads();
    float nk = x * rsqrtf((sredk[0] + sredk[1]) * (1.f / D_) + 1e-6f) * kw[d];
    knorm[(size_t)(t * KV_ + kv) * D_ + d] = nk;
    __shared__ float shk[D_];
    shk[d] = nk;
    __syncthreads();
    float rot = (d < 64) ? -shk[d + 64] : shk[d - 64];
    kbf[(size_t)(t * KV_ + kv) * D_ + d] = f2bf(nk * cosT[t * D_ + d] + rot * sinT[t * D_ + d]);
  }
}

// ---------- k_blk = mean over BS rows of knorm -> bf16 ----------
__global__ __launch_bounds__(128) void kblk_kernel(const float* __restrict__ knorm,
                                                   unsigned short* __restrict__ kblk_bf) {
  int n = blockIdx.x, kv = blockIdx.y, d = threadIdx.x;
  float s = 0.f;
  for (int i = 0; i < BS_; ++i) s += knorm[((size_t)(n * BS_ + i) * KV_ + kv) * D_ + d];
  kblk_bf[(size_t)(n * KV_ + kv) * D_ + d] = f2bf(s * (1.f / BS_));
}

// ---------- fused rope for gk (rows<NB) and gq (rows>=NB) ----------
__global__ __launch_bounds__(128) void rope_g_fused(float* __restrict__ gq, float* __restrict__ gk,
                                                    const float* __restrict__ cosG,
                                                    const float* __restrict__ sinG,
                                                    const float* __restrict__ cosB,
                                                    const float* __restrict__ sinB) {
  int r = blockIdx.x, kvh = blockIdx.y, d = threadIdx.x;
  float* x;
  size_t base;
  float c_, s_;
  if (r < NB_) {
    x = gk;
    base = (size_t)(r * KV_ + kvh) * GH_;
    c_ = cosB[r * GH_ + d]; s_ = sinB[r * GH_ + d];
  } else {
    int rr = r - NB_;
    x = gq;
    base = (size_t)(rr * KV_ + kvh) * GH_;
    c_ = cosG[(size_t)(TG0_ + rr) * GH_ + d]; s_ = sinG[(size_t)(TG0_ + rr) * GH_ + d];
  }
  __shared__ float sh[GH_];
  sh[d] = x[base + d];
  __syncthreads();
  float rot = (d < 64) ? -sh[d + 64] : sh[d - 64];
  x[base + d] = sh[d] * c_ + rot * s_;
}

// ---------- MFMA flash attention v4: 2 waves x 32 rows, split-K by chunk parity ----------
// grid (H, 64): y -> (tile, parity) via quadrant remap so co-resident blocks balance.
// Fixed-max softmax => partials merge by pure addition (merge_o kernel).
// Writes: opart bf16 [p][T][H*D] (unnormalized), lpart fp32 [p][H*T], pooledraw fp32 [H*T*NB].
__global__ __launch_bounds__(128, 2) void attn_mfma(const unsigned short* __restrict__ qbf,
                                                    const unsigned short* __restrict__ kbf,
                                                    const unsigned short* __restrict__ vt,
                                                    unsigned short* __restrict__ opart,
                                                    float* __restrict__ lpart,
                                                    float* __restrict__ pooledraw) {
  int h = blockIdx.x;
  int y = blockIdx.y;
  int tile, p;
  {
    int qd = y >> 4, r = y & 15;
    if (qd == 0)      { tile = r;       p = 0; }
    else if (qd == 1) { tile = 16 + r;  p = 0; }
    else if (qd == 2) { tile = 15 - r;  p = 1; }
    else              { tile = 31 - r;  p = 1; }
  }
  int t0 = tile * 64;
  int tid = threadIdx.x;
  int wid = tid >> 6, lane = tid & 63;
  int quad = lane >> 4, l16 = lane & 15;
  int kv = h >> 1;
  __shared__ unsigned short Ks[64 * 128];   // [key][chunk16 ^ (key&7)]  16KB
  __shared__ unsigned short Vs[128 * 64];   // [d][chunk16 ^ (d&7)]      16KB
  __shared__ unsigned short Ps[2][32 * 64]; // per-wave, stride 64 + XOR swizzle  8KB

  // staging source pointers: 8 K segs (4 keys each) + 8 V segs (8 d-rows each) per wave
  const unsigned short* kbase[8];
  const unsigned short* vbase[8];
#pragma unroll
  for (int it = 0; it < 8; ++it) {
    int seg = wid * 8 + it;
    int krow = seg * 4 + (lane >> 4);
    int kchk = lane & 15;
    kbase[it] = kbf + ((size_t)krow * KV_ + kv) * D_ + ((kchk ^ (krow & 7)) << 3);
    int vrow = seg * 8 + (lane >> 3);
    int vchk = lane & 7;
    vbase[it] = vt + (size_t)(kv * 128 + vrow) * T_ + ((vchk ^ (vrow & 7)) << 3);
  }

  // Q fragments: 32 rows per wave (2 rowsets)
  short8_t qf[2][4];
#pragma unroll
  for (int rs = 0; rs < 2; ++rs) {
    int tq = t0 + wid * 32 + rs * 16 + l16;
#pragma unroll
    for (int kb = 0; kb < 4; ++kb)
      qf[rs][kb] = *(const short8_t*)&qbf[((size_t)tq * H_ + h) * D_ + kb * 32 + quad * 8];
  }

  const short one_bf = (short)0x3F80;
  short8_t ones = {one_bf, one_bf, one_bf, one_bf, one_bf, one_bf, one_bf, one_bf};

  float l_[2][4] = {};
  float pacc[2][2][4] = {};  // [half16][rs][reg]
  float4_t o[2][8];
#pragma unroll
  for (int rs = 0; rs < 2; ++rs)
#pragma unroll
    for (int j = 0; j < 8; ++j) o[rs][j] = (float4_t){0.f, 0.f, 0.f, 0.f};

  for (int c = p; c <= tile; c += 2) {
    __syncthreads();  // previous compute done; LDS free
#pragma unroll
    for (int it = 0; it < 8; ++it) {
      gload16(kbase[it] + (size_t)c * 65536, Ks + (wid * 8 + it) * 512);
      gload16(vbase[it] + c * 64, Vs + (wid * 8 + it) * 512);
    }
    __syncthreads();  // chunk staged (vmcnt(0) drained by barrier semantics)

    // ---- QK^T: S 32x64 per wave ----
    float4_t s[4][2];
#pragma unroll
    for (int j = 0; j < 4; ++j) {
      short8_t kf[4];
#pragma unroll
      for (int kb = 0; kb < 4; ++kb)
        kf[kb] = *(const short8_t*)&Ks[(j * 16 + l16) * 128 + (((kb * 4 + quad) ^ (l16 & 7)) << 3)];
#pragma unroll
      for (int rs = 0; rs < 2; ++rs) {
        float4_t a = (float4_t){0.f, 0.f, 0.f, 0.f};
#pragma unroll
        for (int kb = 0; kb < 4; ++kb)
          a = __builtin_amdgcn_mfma_f32_16x16x32_bf16(qf[rs][kb], kf[kb], a, 0, 0, 0);
        s[j][rs] = a;
      }
    }
    // ---- p = exp(logit - MFIX); causal mask only on diagonal chunk ----
    if (c == tile) {
#pragma unroll
      for (int rs = 0; rs < 2; ++rs)
#pragma unroll
        for (int reg = 0; reg < 4; ++reg) {
          int trow = t0 + wid * 32 + rs * 16 + quad * 4 + reg;
#pragma unroll
          for (int j = 0; j < 4; ++j) {
            float pv = __expf(s[j][rs][reg] * SCALE_ - MFIX_);
            s[j][rs][reg] = (c * 64 + j * 16 + l16 <= trow) ? pv : 0.f;
          }
        }
    } else {
#pragma unroll
      for (int j = 0; j < 4; ++j)
#pragma unroll
        for (int rs = 0; rs < 2; ++rs)
#pragma unroll
          for (int reg = 0; reg < 4; ++reg)
            s[j][rs][reg] = __expf(s[j][rs][reg] * SCALE_ - MFIX_);
    }
    // ---- P (C layout) -> per-wave LDS, stride 64 + chunk XOR swizzle ----
#pragma unroll
    for (int j = 0; j < 4; ++j)
#pragma unroll
      for (int rs = 0; rs < 2; ++rs)
#pragma unroll
        for (int reg = 0; reg < 4; ++reg) {
          int rr = rs * 16 + quad * 4 + reg;
          Ps[wid][rr * 64 + ((((j * 2) + (l16 >> 3)) ^ (rr & 7)) << 3) + (l16 & 7)] =
              f2bf(s[j][rs][reg]);
        }
    // ---- PV + row-sum via all-ones MFMA ----
    float4_t pool[2];
    pool[0] = (float4_t){0.f, 0.f, 0.f, 0.f};
    pool[1] = (float4_t){0.f, 0.f, 0.f, 0.f};
#pragma unroll
    for (int ks = 0; ks < 2; ++ks) {
      short8_t pf[2];
#pragma unroll
      for (int rs = 0; rs < 2; ++rs) {
        int rr = rs * 16 + l16;
        pf[rs] = *(const short8_t*)&Ps[wid][rr * 64 + (((ks * 4 + quad) ^ (rr & 7)) << 3)];
        pool[rs] = __builtin_amdgcn_mfma_f32_16x16x32_bf16(pf[rs], ones, pool[rs], 0, 0, 0);
      }
#pragma unroll
      for (int jt = 0; jt < 8; ++jt) {
        short8_t vf = *(const short8_t*)&Vs[(jt * 16 + l16) * 64 + (((ks * 4 + quad) ^ (l16 & 7)) << 3)];
#pragma unroll
        for (int rs = 0; rs < 2; ++rs)
          o[rs][jt] = __builtin_amdgcn_mfma_f32_16x16x32_bf16(pf[rs], vf, o[rs][jt], 0, 0, 0);
      }
    }
    int half16 = (c >> 4) & 1, cl = c & 15;
#pragma unroll
    for (int rs = 0; rs < 2; ++rs)
#pragma unroll
      for (int reg = 0; reg < 4; ++reg) {
        l_[rs][reg] += pool[rs][reg];
        if (l16 == cl) pacc[half16][rs][reg] = pool[rs][reg];
      }
  }
  // ---- epilogue: unnormalized partials ----
  unsigned short* op = opart + (size_t)p * (T_ * H_ * D_);
#pragma unroll
  for (int rs = 0; rs < 2; ++rs)
#pragma unroll
    for (int jt = 0; jt < 8; ++jt)
#pragma unroll
      for (int reg = 0; reg < 4; ++reg) {
        int trow = t0 + wid * 32 + rs * 16 + quad * 4 + reg;
        op[(size_t)trow * (H_ * D_) + h * D_ + jt * 16 + l16] = f2bf(o[rs][jt][reg]);
      }
  if (l16 == 0) {
#pragma unroll
    for (int rs = 0; rs < 2; ++rs)
#pragma unroll
      for (int reg = 0; reg < 4; ++reg) {
        int trow = t0 + wid * 32 + rs * 16 + quad * 4 + reg;
        lpart[p * HT_ + h * T_ + trow] = l_[rs][reg];
      }
  }
  if ((l16 & 1) == p) {
#pragma unroll
    for (int rs = 0; rs < 2; ++rs)
#pragma unroll
      for (int reg = 0; reg < 4; ++reg) {
        int trow = t0 + wid * 32 + rs * 16 + quad * 4 + reg;
        pooledraw[((size_t)h * T_ + trow) * NB_ + l16] = pacc[0][rs][reg];
        pooledraw[((size_t)h * T_ + trow) * NB_ + 16 + l16] = pacc[1][rs][reg];
      }
  }
}

// ---------- merge split-K partials: attnb = (O_a + O_b) / (l_a + l_b) ----------
__global__ __launch_bounds__(256) void merge_o(const unsigned short* __restrict__ opart,
                                               const float* __restrict__ lpart,
                                               unsigned short* __restrict__ attnb) {
  int i = (blockIdx.x * 256 + threadIdx.x) * 4;
  int t = i >> 11, h = (i & 2047) >> 7;
  float inv = 1.f / (lpart[h * T_ + t] + lpart[HT_ + h * T_ + t]);
  ushort4_t a = *(const ushort4_t*)(opart + i);
  ushort4_t b = *(const ushort4_t*)(opart + (size_t)(T_ * H_ * D_) + i);
  ushort4_t r;
#pragma unroll
  for (int k = 0; k < 4; ++k) r[k] = f2bf((bf2f(a[k]) + bf2f(b[k])) * inv);
  *(ushort4_t*)(attnb + i) = r;
}

// ---------- gate loss: 8 t per block (half-wave per t), normalizes pooled via lpart ----------
__global__ __launch_bounds__(256) void gate_loss2(const float* __restrict__ gq,
                                                  const float* __restrict__ gk,
                                                  const float* __restrict__ pooledraw,
                                                  const float* __restrict__ lpart,
                                                  float* __restrict__ klsum) {
  int kv = blockIdx.x;
  int sub = threadIdx.x >> 5;
  int n = threadIdx.x & 31;
  int tloc = blockIdx.y * 8 + sub;
  bool act = tloc < (T_ - START_);
  int t = START_ + (act ? tloc : 0);
  const float4* a = (const float4*)(gq + ((size_t)(t - TG0_) * KV_ + kv) * GH_);
  const float4* b = (const float4*)(gk + (size_t)(n * KV_ + kv) * GH_);
  float dot = 0.f;
#pragma unroll
  for (int d4 = 0; d4 < 32; ++d4) {
    float4 av = a[d4], bv = b[d4];
    dot += av.x * bv.x + av.y * bv.y + av.z * bv.z + av.w * bv.w;
  }
  bool valid = (t / BS_) >= n;
  float score = valid ? dot * SCALE_ : -1e9f;
  float M = score;
#pragma unroll
  for (int o = 16; o > 0; o >>= 1) M = fmaxf(M, __shfl_xor(M, o, 64));
  float e = __expf(score - M);
  float Z = e;
#pragma unroll
  for (int o = 16; o > 0; o >>= 1) Z += __shfl_xor(Z, o, 64);
  float logZ = M + logf(Z);
  float g = 0.f;
  if (valid) {
    int h0 = kv * G_, h1 = h0 + 1;
    float inv0 = 1.f / (lpart[h0 * T_ + t] + lpart[HT_ + h0 * T_ + t]);
    float inv1 = 1.f / (lpart[h1 * T_ + t] + lpart[HT_ + h1 * T_ + t]);
    float p0 = pooledraw[((size_t)h0 * T_ + t) * NB_ + n] * inv0;
    float p1 = pooledraw[((size_t)h1 * T_ + t) * NB_ + n] * inv1;
    g = fmaxf(p0, p1);
  }
  float gs = g;
#pragma unroll
  for (int o = 16; o > 0; o >>= 1) gs += __shfl_xor(gs, o, 64);
  float tgt = g / (gs + 1e-9f);
  float kl = (tgt > 0.f) ? tgt * (logf(tgt) - (score - logZ)) : 0.f;
  float ks = kl;
#pragma unroll
  for (int o = 16; o > 0; o >>= 1) ks += __shfl_xor(ks, o, 64);
  if (n == 0 && act) klsum[kv * (T_ - START_) + tloc] = ks;
}

__global__ __launch_bounds__(256) void finalize_loss(const float* __restrict__ klsum,
                                                     float* __restrict__ out) {
  const int n = KV_ * (T_ - START_);
  float s = 0.f;
  for (int i = threadIdx.x; i < n; i += 256) s += klsum[i];
  s = wave_sum(s);
  __shared__ float sh[4];
  if ((threadIdx.x & 63) == 0) sh[threadIdx.x >> 6] = s;
  __syncthreads();
  if (threadIdx.x == 0)
    out[0] = (sh[0] + sh[1] + sh[2] + sh[3]) * (1.f / ((float)(T_ - START_) * NB_));
}

extern "C" void kernel_launch(void* const* d_in, const int* in_sizes, int n_in,
                              void* d_out, int out_size, void* d_ws, size_t ws_size,
                              hipStream_t stream) {
  const float* hs   = (const float*)d_in[0];
  const float* Wq   = (const float*)d_in[1];
  const float* Wk   = (const float*)d_in[2];
  const float* Wv   = (const float*)d_in[3];
  const float* Wo   = (const float*)d_in[4];
  const float* qw   = (const float*)d_in[5];
  const float* kw   = (const float*)d_in[6];
  const float* gwq  = (const float*)d_in[7];
  const float* gwk  = (const float*)d_in[8];
  const float* cosT = (const float*)d_in[9];
  const float* sinT = (const float*)d_in[10];
  const float* cosG = (const float*)d_in[11];
  const float* sinG = (const float*)d_in[12];
  const float* cosB = (const float*)d_in[13];
  const float* sinB = (const float*)d_in[14];
  float* out = (float*)d_out;
  float* ws = (float*)d_ws;
  const size_t MEG = 1048576;

  // ---- workspace layout (float offsets), lifetime-aliased ----
  float*          qkvf      = ws;                                 // [0,8M): [T][4096] fp32
  unsigned short* opart     = (unsigned short*)ws;                //   alias: 8.39M ush = [0,4M fl)
  unsigned short* attnb     = (unsigned short*)(ws + 4 * MEG);    //   alias: [4M,6M fl)
  float*          pooledraw = ws + 6 * MEG;                       //   alias: [6M,7M)
  float*          lpart     = ws + 7 * MEG;                       //   alias: 64K floats
  float*          klsum     = ws + 7 * MEG + 65536;               //   alias: 16K floats
  unsigned short* WqkvT     = (unsigned short*)(ws + 8 * MEG);    // [8M,12M): 8M ushorts
  unsigned short* qbf       = WqkvT;                              //   alias after qkv gemm
  unsigned short* kbf       = WqkvT + 4 * MEG;
  unsigned short* vt        = WqkvT + 6 * MEG;
  unsigned short* hsb       = (unsigned short*)(ws + 12 * MEG);   // [12M,14M)
  float*          knorm     = ws + 12 * MEG;                      //   alias after qkv gemm
  unsigned short* WoT       = (unsigned short*)(ws + 14 * MEG);   // [14M,16M)
  unsigned short* qpool_bf  = (unsigned short*)(ws + 16 * MEG);   // [16M,...)
  float*          gq        = ws + 17 * MEG;
  unsigned short* kblk_bf   = (unsigned short*)(ws + 18 * MEG + 786432);
  float*          gk        = ws + 18 * MEG + 819200;
  unsigned short* gwqT      = (unsigned short*)(ws + 18 * MEG + 851968);
  unsigned short* gwkT      = (unsigned short*)(ws + 18 * MEG + 860160);

  prep_cast<<<7176, 256, 0, stream>>>(hs, Wq, Wk, Wv, Wo, gwq, gwk, hsb, WqkvT, WoT, gwqT, gwkT);
  gemm_bf16_v3<<<dim3(32, 16), 256, 0, stream>>>(hsb, WqkvT, qkvf, 2048, 4096, 2048, 4096);
  norm_rope_fused<<<dim3(T_, 16), 128, 0, stream>>>(qkvf, qw, kw, cosT, sinT, qbf, qpool_bf,
                                                    kbf, knorm);
  castT<<<dim3(16, 32), 256, 0, stream>>>(qkvf + 3072, vt, T_, 1024, 4096);
  kblk_kernel<<<dim3(NB_, KV_), 128, 0, stream>>>(knorm, kblk_bf);
  gemm_bf16_v3<<<dim3(1, 104), 256, 0, stream>>>(qpool_bf, gwqT, gq, 13312, 128, 128, 128);
  gemm_bf16_v3<<<dim3(1, 2), 256, 0, stream>>>(kblk_bf, gwkT, gk, 256, 128, 128, 128);
  rope_g_fused<<<dim3(NB_ + (T_ - TG0_), KV_), 128, 0, stream>>>(gq, gk, cosG, sinG, cosB, sinB);
  attn_mfma<<<dim3(H_, 64), 128, 0, stream>>>(qbf, kbf, vt, opart, lpart, pooledraw);
  merge_o<<<4096, 256, 0, stream>>>(opart, lpart, attnb);
  gemm_bf16_v3<<<dim3(16, 16), 256, 0, stream>>>(attnb, WoT, out, 2048, 2048, 2048, 2048);
  gate_loss2<<<dim3(KV_, 205), 256, 0, stream>>>(gq, gk, pooledraw, lpart, klsum);
  finalize_loss<<<1, 256, 0, stream>>>(klsum, out + (size_t)T_ * HID_);
}